// Round 12
// baseline (201.607 us; speedup 1.0000x reference)
//
#include <hip/hip_runtime.h>
#include <hip/hip_bf16.h>
#include <hip/hip_fp16.h>

#define N_NODES_C 100000
#define NSCAN     102400      // N padded to 25 * 4096 for the scan
#define SCAN_BS   1024        // threads per scan block (4 elems each -> 4096/block)
#define NB_SCAN   (NSCAN / (SCAN_BS * 4))   // 25 blocks

typedef unsigned u32x4 __attribute__((ext_vector_type(4)));

// ---------------------------------------------------------------------------
// fp16 helpers: h_src stored as packed fp16 (uint = 2 halves)
// ---------------------------------------------------------------------------
union U2H { unsigned u; __half2 h; };

__device__ __forceinline__ __half2 addp(__half2 a, unsigned u)
{
    U2H c; c.u = u;
    return __hadd2(a, c.h);
}

// h_src f32 -> packed fp16 copy; row N_NODES_C is written as zeros (pad row)
__global__ __launch_bounds__(256) void convert_fp16(
    const float* __restrict__ x, uint4* __restrict__ y, int n8)
{
    int i = blockIdx.x * 256 + threadIdx.x;
    if (i >= n8 + 8) return;
    if (i >= n8) { y[i] = make_uint4(0u, 0u, 0u, 0u); return; }
    const float4* x4 = reinterpret_cast<const float4*>(x);
    float4 a = x4[i * 2 + 0];
    float4 b = x4[i * 2 + 1];
    U2H c0, c1, c2, c3;
    c0.h = __floats2half2_rn(a.x, a.y);
    c1.h = __floats2half2_rn(a.z, a.w);
    c2.h = __floats2half2_rn(b.x, b.y);
    c3.h = __floats2half2_rn(b.z, b.w);
    uint4 o;
    o.x = c0.u; o.y = c1.u; o.z = c2.u; o.w = c3.u;
    y[i] = o;
}

// ---------------------------------------------------------------------------
// CSR build (padded-to-4 segments):
// histogram(+rank) -> block scan of PADDED counts -> scan_add (+pad fill) -> fill
// ---------------------------------------------------------------------------
__global__ __launch_bounds__(256) void edge_hist(
    const int* __restrict__ dst, int* __restrict__ counts,
    int* __restrict__ rank, int n_edges)
{
    int i = blockIdx.x * 256 + threadIdx.x;
    int b4 = i * 4;
    if (b4 + 3 < n_edges) {
        int4 d = reinterpret_cast<const int4*>(dst)[i];
        int4 rk;
        rk.x = atomicAdd(&counts[d.x], 1);
        rk.y = atomicAdd(&counts[d.y], 1);
        rk.z = atomicAdd(&counts[d.z], 1);
        rk.w = atomicAdd(&counts[d.w], 1);
        reinterpret_cast<int4*>(rank)[i] = rk;
    } else {
        for (int e = b4; e < n_edges; ++e)
            rank[e] = atomicAdd(&counts[dst[e]], 1);
    }
}

__global__ __launch_bounds__(SCAN_BS) void scan_block(
    const int* __restrict__ counts, int* __restrict__ offsets,
    int* __restrict__ partials)
{
    __shared__ int sd[2][SCAN_BS];
    int t = threadIdx.x, b = blockIdx.x;
    int4 c = reinterpret_cast<const int4*>(counts)[b * SCAN_BS + t];
    int q0 = (c.x + 3) & ~3;
    int q1 = (c.y + 3) & ~3;
    int q2 = (c.z + 3) & ~3;
    int q3 = (c.w + 3) & ~3;
    int tot = q0 + q1 + q2 + q3;
    sd[0][t] = tot;
    __syncthreads();
    int pin = 0;
    #pragma unroll
    for (int off = 1; off < SCAN_BS; off <<= 1) {
        int v = sd[pin][t];
        if (t >= off) v += sd[pin][t - off];
        sd[pin ^ 1][t] = v;
        pin ^= 1;
        __syncthreads();
    }
    int incl = sd[pin][t];      // inclusive scan of per-thread padded sums
    int excl = incl - tot;
    int4 o;
    o.x = excl;
    o.y = excl + q0;
    o.z = excl + q0 + q1;
    o.w = excl + q0 + q1 + q2;
    reinterpret_cast<int4*>(offsets)[b * SCAN_BS + t] = o;
    if (t == SCAN_BS - 1) partials[b] = incl;
}

// add block bases; also fill each node's pad slots with the dummy index N
__global__ __launch_bounds__(SCAN_BS) void scan_add(
    int* __restrict__ offsets, const int* __restrict__ partials,
    const int* __restrict__ counts, int* __restrict__ edge_src)
{
    __shared__ int base_s;
    int b = blockIdx.x;
    if (threadIdx.x == 0) {
        int s = 0;
        for (int i = 0; i < b; ++i) s += partials[i];
        base_s = s;
    }
    __syncthreads();
    int i = b * SCAN_BS + threadIdx.x;
    int4 v = reinterpret_cast<int4*>(offsets)[i];
    v.x += base_s; v.y += base_s; v.z += base_s; v.w += base_s;
    reinterpret_cast<int4*>(offsets)[i] = v;
    int4 c = reinterpret_cast<const int4*>(counts)[i];
    int s, ep;
    s = v.x + c.x; ep = v.x + ((c.x + 3) & ~3); for (; s < ep; ++s) edge_src[s] = N_NODES_C;
    s = v.y + c.y; ep = v.y + ((c.y + 3) & ~3); for (; s < ep; ++s) edge_src[s] = N_NODES_C;
    s = v.z + c.z; ep = v.z + ((c.z + 3) & ~3); for (; s < ep; ++s) edge_src[s] = N_NODES_C;
    s = v.w + c.w; ep = v.w + ((c.w + 3) & ~3); for (; s < ep; ++s) edge_src[s] = N_NODES_C;
}

__global__ __launch_bounds__(256) void edge_fill(
    const int* __restrict__ src, const int* __restrict__ dst,
    const int* __restrict__ rank, const int* __restrict__ offsets,
    int* __restrict__ edge_src, int n_edges)
{
    int i = blockIdx.x * 256 + threadIdx.x;
    int b4 = i * 4;
    if (b4 + 3 < n_edges) {
        int4 s  = reinterpret_cast<const int4*>(src)[i];
        int4 d  = reinterpret_cast<const int4*>(dst)[i];
        int4 rk = reinterpret_cast<const int4*>(rank)[i];
        edge_src[offsets[d.x] + rk.x] = s.x;
        edge_src[offsets[d.y] + rk.y] = s.y;
        edge_src[offsets[d.z] + rk.z] = s.z;
        edge_src[offsets[d.w] + rk.w] = s.w;
    } else {
        for (int e = b4; e < n_edges; ++e)
            edge_src[offsets[dst[e]] + rank[e]] = src[e];
    }
}

// ---------------------------------------------------------------------------
// Fused gather-mean + GEMM, 2-deep-rows / 1-deep-idx software pipeline.
// Steady-state FIFO invariant (17 outstanding): rows(k)x8, idx(k+2), rows(k+1)x8
//   vmcnt(9)  -> rows(k) done (issued 2 iterations ago: consume->reissue trick)
//   consume rows(k) from buffer P (k mod 2)
//   vmcnt(8)  -> idx(k+2) done (issued 1 full iteration ago)
//   ADDR(k+2); issue idx(k+3); issue rows(k+2) into buffer P (just freed)
// Never drains below 8 in steady state. Wave-uniform nmax + zero pad-row
// keeps control flow uniform so the FIFO counts are exact.
// ---------------------------------------------------------------------------

#define GL_ROWS(P0,P1,P2,P3,P4,P5,P6,P7) \
    asm volatile( \
        "global_load_dwordx4 %0, %8, off\n\t" \
        "global_load_dwordx4 %1, %9, off\n\t" \
        "global_load_dwordx4 %2, %10, off\n\t" \
        "global_load_dwordx4 %3, %11, off\n\t" \
        "global_load_dwordx4 %4, %8, off offset:64\n\t" \
        "global_load_dwordx4 %5, %9, off offset:64\n\t" \
        "global_load_dwordx4 %6, %10, off offset:64\n\t" \
        "global_load_dwordx4 %7, %11, off offset:64" \
        : "=&v"(P0), "=&v"(P1), "=&v"(P2), "=&v"(P3), \
          "=&v"(P4), "=&v"(P5), "=&v"(P6), "=&v"(P7) \
        : "v"(a0), "v"(a1), "v"(a2), "v"(a3))

#define GL_IDX() do { \
    asm volatile("global_load_dwordx4 %0, %1, off" \
        : "=&v"(idxQ) : "v"((const int*)(edge_src + e))); \
    e += 4; \
} while (0)

#define WAITQ(n,P0,P1,P2,P3,P4,P5,P6,P7) \
    asm volatile("s_waitcnt vmcnt(" #n ")" \
        : "+v"(P0), "+v"(P1), "+v"(P2), "+v"(P3), \
          "+v"(P4), "+v"(P5), "+v"(P6), "+v"(P7))

#define WAITIDX(n) asm volatile("s_waitcnt vmcnt(" #n ")" : "+v"(idxQ))

#define ADDRK(KK) do { \
    bool ok_ = (KK) < nit; \
    a0 = ok_ ? (hsb + ((size_t)(int)idxQ[0] * 8 + j)) : zrow; \
    a1 = ok_ ? (hsb + ((size_t)(int)idxQ[1] * 8 + j)) : zrow; \
    a2 = ok_ ? (hsb + ((size_t)(int)idxQ[2] * 8 + j)) : zrow; \
    a3 = ok_ ? (hsb + ((size_t)(int)idxQ[3] * 8 + j)) : zrow; \
} while (0)

#define CONSQ(P0,P1,P2,P3,P4,P5,P6,P7) do { \
    acL[0] = addp(acL[0], P0[0]); acL[1] = addp(acL[1], P0[1]); \
    acL[2] = addp(acL[2], P0[2]); acL[3] = addp(acL[3], P0[3]); \
    acL[0] = addp(acL[0], P1[0]); acL[1] = addp(acL[1], P1[1]); \
    acL[2] = addp(acL[2], P1[2]); acL[3] = addp(acL[3], P1[3]); \
    acL[0] = addp(acL[0], P2[0]); acL[1] = addp(acL[1], P2[1]); \
    acL[2] = addp(acL[2], P2[2]); acL[3] = addp(acL[3], P2[3]); \
    acL[0] = addp(acL[0], P3[0]); acL[1] = addp(acL[1], P3[1]); \
    acL[2] = addp(acL[2], P3[2]); acL[3] = addp(acL[3], P3[3]); \
    acH[0] = addp(acH[0], P4[0]); acH[1] = addp(acH[1], P4[1]); \
    acH[2] = addp(acH[2], P4[2]); acH[3] = addp(acH[3], P4[3]); \
    acH[0] = addp(acH[0], P5[0]); acH[1] = addp(acH[1], P5[1]); \
    acH[2] = addp(acH[2], P5[2]); acH[3] = addp(acH[3], P5[3]); \
    acH[0] = addp(acH[0], P6[0]); acH[1] = addp(acH[1], P6[1]); \
    acH[2] = addp(acH[2], P6[2]); acH[3] = addp(acH[3], P6[3]); \
    acH[0] = addp(acH[0], P7[0]); acH[1] = addp(acH[1], P7[1]); \
    acH[2] = addp(acH[2], P7[2]); acH[3] = addp(acH[3], P7[3]); \
} while (0)

// consume group k from buffer P, issue idx(k+3) and rows(k+2) back into P
#define BODY(P0,P1,P2,P3,P4,P5,P6,P7, KNEXT) do { \
    WAITQ(9, P0,P1,P2,P3,P4,P5,P6,P7); \
    CONSQ(P0,P1,P2,P3,P4,P5,P6,P7); \
    WAITIDX(8); \
    ADDRK(KNEXT); \
    GL_IDX(); \
    GL_ROWS(P0,P1,P2,P3,P4,P5,P6,P7); \
} while (0)

__global__ __launch_bounds__(256) void sage_fused(
    const uint4* __restrict__ hsb,      // packed fp16 h_src [(N+1)][8] uint4
    const float* __restrict__ h_dst,
    const int*   __restrict__ offsets,  // padded CSR offsets
    const int*   __restrict__ counts,   // raw degrees
    const int*   __restrict__ edge_src, // padded edge lists
    const float* __restrict__ weight,   // [64][128] row-major
    const float* __restrict__ bias,     // [64]
    float*       __restrict__ out,      // [N][64]
    int n_nodes)
{
    __shared__ float4 x4[64 * 32];   // x4[r][c] at r*32 + ((c + r) & 31)

    const int t    = threadIdx.x;
    const int base = blockIdx.x * 64;

    // stage h_dst (cols 0..15): 4 float4 per thread
    #pragma unroll
    for (int q = 0; q < 4; ++q) {
        int idx = t + q * 256;        // 0..1023
        int r   = idx >> 4;
        int k4  = idx & 15;
        int g   = base + r;
        float4 xv = make_float4(0.f, 0.f, 0.f, 0.f);
        if (g < n_nodes)
            xv = reinterpret_cast<const float4*>(h_dst)[(size_t)g * 16 + k4];
        x4[r * 32 + ((k4 + r) & 31)] = xv;
    }

    // gather neighbor mean (cols 16..31)
    {
        const int j = t & 3;          // uint4 chunk pair: j and j+4
        const int r = t >> 2;         // node within tile (0..63)
        const int g = base + r;       // < NSCAN always; may be >= n_nodes (deg 0)
        __half2 acL[4], acH[4];
        const __half2 z = __floats2half2_rn(0.f, 0.f);
        #pragma unroll
        for (int q = 0; q < 4; ++q) { acL[q] = z; acH[q] = z; }

        int e0  = offsets[g];
        int e1  = offsets[g + 1];
        int nit = (e1 - e0) >> 2;     // padded -> exact
        int deg = counts[g];

        int nmax = nit;               // wave-uniform trip count
        #pragma unroll
        for (int off = 4; off < 64; off <<= 1) {
            int o = __shfl_xor(nmax, off, 64);
            nmax = nmax > o ? nmax : o;
        }

        const uint4* zrow = hsb + ((size_t)N_NODES_C * 8 + j);
        const uint4 *a0 = zrow, *a1 = zrow, *a2 = zrow, *a3 = zrow;
        u32x4 PA0, PA1, PA2, PA3, PA4, PA5, PA6, PA7;
        u32x4 PB0, PB1, PB2, PB3, PB4, PB5, PB6, PB7;
        u32x4 idxQ;
        int e = e0;

        if (nmax == 1) {
            GL_IDX();
            WAITIDX(0);
            ADDRK(0);
            GL_ROWS(PA0,PA1,PA2,PA3,PA4,PA5,PA6,PA7);
            WAITQ(0, PA0,PA1,PA2,PA3,PA4,PA5,PA6,PA7);
            CONSQ(PA0,PA1,PA2,PA3,PA4,PA5,PA6,PA7);
        } else if (nmax == 2) {
            GL_IDX();                  // idx0
            WAITIDX(0); ADDRK(0);
            GL_IDX();                  // idx1
            GL_ROWS(PA0,PA1,PA2,PA3,PA4,PA5,PA6,PA7);   // rows0
            WAITIDX(8); ADDRK(1);      // idx1 done, rows0 in flight
            GL_ROWS(PB0,PB1,PB2,PB3,PB4,PB5,PB6,PB7);   // rows1
            WAITQ(8, PA0,PA1,PA2,PA3,PA4,PA5,PA6,PA7);  // rows0 done
            CONSQ(PA0,PA1,PA2,PA3,PA4,PA5,PA6,PA7);
            WAITQ(0, PB0,PB1,PB2,PB3,PB4,PB5,PB6,PB7);
            CONSQ(PB0,PB1,PB2,PB3,PB4,PB5,PB6,PB7);
        } else if (nmax > 2) {
            // prologue: establish FIFO rows0(8), idx2, rows1(8)
            GL_IDX();                  // idx0
            WAITIDX(0); ADDRK(0);
            GL_IDX();                  // idx1
            GL_ROWS(PA0,PA1,PA2,PA3,PA4,PA5,PA6,PA7);   // rows0
            WAITIDX(8); ADDRK(1);      // idx1 done (rows0 in flight)
            GL_IDX();                  // idx2
            GL_ROWS(PB0,PB1,PB2,PB3,PB4,PB5,PB6,PB7);   // rows1
            int nb = nmax - 2;         // body count
            int k;
            if (nb & 1) {
                BODY(PA0,PA1,PA2,PA3,PA4,PA5,PA6,PA7, 2);
                for (k = 1; k < nb; k += 2) {
                    BODY(PB0,PB1,PB2,PB3,PB4,PB5,PB6,PB7, k + 2);
                    BODY(PA0,PA1,PA2,PA3,PA4,PA5,PA6,PA7, k + 3);
                }
                WAITQ(9, PB0,PB1,PB2,PB3,PB4,PB5,PB6,PB7);
                CONSQ(PB0,PB1,PB2,PB3,PB4,PB5,PB6,PB7);
                WAITQ(0, PA0,PA1,PA2,PA3,PA4,PA5,PA6,PA7);
                CONSQ(PA0,PA1,PA2,PA3,PA4,PA5,PA6,PA7);
            } else {
                for (k = 0; k < nb; k += 2) {
                    BODY(PA0,PA1,PA2,PA3,PA4,PA5,PA6,PA7, k + 2);
                    BODY(PB0,PB1,PB2,PB3,PB4,PB5,PB6,PB7, k + 3);
                }
                WAITQ(9, PA0,PA1,PA2,PA3,PA4,PA5,PA6,PA7);
                CONSQ(PA0,PA1,PA2,PA3,PA4,PA5,PA6,PA7);
                WAITQ(0, PB0,PB1,PB2,PB3,PB4,PB5,PB6,PB7);
                CONSQ(PB0,PB1,PB2,PB3,PB4,PB5,PB6,PB7);
            }
        }

        float invd = 1.0f / (float)(deg > 1 ? deg : 1);
        float4 w0 = make_float4(__low2float(acL[0]) * invd,
                                __high2float(acL[0]) * invd,
                                __low2float(acL[1]) * invd,
                                __high2float(acL[1]) * invd);
        float4 w1 = make_float4(__low2float(acL[2]) * invd,
                                __high2float(acL[2]) * invd,
                                __low2float(acL[3]) * invd,
                                __high2float(acL[3]) * invd);
        float4 w2 = make_float4(__low2float(acH[0]) * invd,
                                __high2float(acH[0]) * invd,
                                __low2float(acH[1]) * invd,
                                __high2float(acH[1]) * invd);
        float4 w3 = make_float4(__low2float(acH[2]) * invd,
                                __high2float(acH[2]) * invd,
                                __low2float(acH[3]) * invd,
                                __high2float(acH[3]) * invd);
        x4[r * 32 + (((16 + 2 * j) + r) & 31)] = w0;
        x4[r * 32 + (((17 + 2 * j) + r) & 31)] = w1;
        x4[r * 32 + (((24 + 2 * j) + r) & 31)] = w2;
        x4[r * 32 + (((25 + 2 * j) + r) & 31)] = w3;
    }
    __syncthreads();

    // GEMM: thread tile = 4 nodes x 4 outs; W streamed from global (L1)
    const int m  = t & 15;    // out-group: o0 = 4m
    const int r0 = t >> 4;    // node base: rows r0 + 16*i
    const int o0 = m * 4;

    const float4* w4g = reinterpret_cast<const float4*>(weight);
    float4 bv = reinterpret_cast<const float4*>(bias)[m];

    float acc[4][4];
    #pragma unroll
    for (int i = 0; i < 4; ++i) {
        acc[i][0] = bv.x; acc[i][1] = bv.y; acc[i][2] = bv.z; acc[i][3] = bv.w;
    }

    #pragma unroll 4
    for (int k4 = 0; k4 < 32; ++k4) {
        float4 wv[4];
        #pragma unroll
        for (int jj = 0; jj < 4; ++jj)
            wv[jj] = w4g[(o0 + jj) * 32 + k4];
        #pragma unroll
        for (int i = 0; i < 4; ++i) {
            int r = r0 + 16 * i;
            float4 xv = x4[r * 32 + ((k4 + r) & 31)];
            #pragma unroll
            for (int jj = 0; jj < 4; ++jj) {
                acc[i][jj] += xv.x * wv[jj].x + xv.y * wv[jj].y
                            + xv.z * wv[jj].z + xv.w * wv[jj].w;
            }
        }
    }

    #pragma unroll
    for (int i = 0; i < 4; ++i) {
        int g = base + r0 + 16 * i;
        if (g < n_nodes) {
            float4 ov = make_float4(acc[i][0], acc[i][1], acc[i][2], acc[i][3]);
            reinterpret_cast<float4*>(out)[(size_t)g * 16 + m] = ov;
        }
    }
}

// ---------------------------------------------------------------------------
extern "C" void kernel_launch(void* const* d_in, const int* in_sizes, int n_in,
                              void* d_out, int out_size, void* d_ws, size_t ws_size,
                              hipStream_t stream)
{
    const float* h_src  = (const float*)d_in[0];
    const float* h_dst  = (const float*)d_in[1];
    const int*   src    = (const int*)d_in[2];
    const int*   dst    = (const int*)d_in[3];
    const float* weight = (const float*)d_in[4];
    const float* bias   = (const float*)d_in[5];
    float*       out    = (float*)d_out;

    const int n_edges = in_sizes[2];
    const int n_feat  = in_sizes[0];   // N*64 floats

    // workspace layout (ints); all vector bases 16B-aligned
    int*   counts   = (int*)d_ws;                         // NSCAN
    int*   offsets  = counts   + NSCAN;                   // NSCAN
    int*   partials = offsets  + NSCAN;                   // 64
    int*   rank     = partials + 64;                      // n_edges
    int*   edge_src = rank     + n_edges;                 // n_edges + 3*NSCAN + 64 (pads + prefetch slack)
    uint4* hsb      = (uint4*)(edge_src + n_edges + 3 * NSCAN + 64);  // (N+1)*8 uint4

    // zero the histogram (ws is poisoned; everything else is fully rewritten)
    hipMemsetAsync(counts, 0, NSCAN * sizeof(int), stream);

    int n8 = n_feat / 8;   // 800000
    convert_fp16<<<(n8 + 8 + 255) / 256, 256, 0, stream>>>(h_src, hsb, n8);

    int nbE4 = ((n_edges + 3) / 4 + 255) / 256;
    edge_hist<<<nbE4, 256, 0, stream>>>(dst, counts, rank, n_edges);
    scan_block<<<NB_SCAN, SCAN_BS, 0, stream>>>(counts, offsets, partials);
    scan_add<<<NB_SCAN, SCAN_BS, 0, stream>>>(offsets, partials, counts, edge_src);
    edge_fill<<<nbE4, 256, 0, stream>>>(src, dst, rank, offsets, edge_src, n_edges);

    sage_fused<<<(N_NODES_C + 63) / 64, 256, 0, stream>>>(
        hsb, h_dst, offsets, counts, edge_src, weight, bias, out, N_NODES_C);
}